// Round 1
// baseline (4236.718 us; speedup 1.0000x reference)
//
#include <hip/hip_runtime.h>
#include <hip/hip_bf16.h>
#include <math.h>

// Problem constants
#define Bq 4
#define Sq 1024
#define Eq 1024
#define Hq 16
#define Dq 64

// ---------------------------------------------------------------------------
// GEMM: C[M,N] = (A[M,K] @ Bw[N,K]^T + bias[N]) * scale   (torch Linear style)
// 64x64 tile, BK=16, 256 threads, 4x4 register micro-tile. fp32.
// ---------------------------------------------------------------------------
#define TILE 64
#define BK 16
#define APAD 68  // 64 + 4 pad: keeps 16B alignment for b128 reads, kills bank conflicts

__global__ __launch_bounds__(256) void gemm_bt(
    const float* __restrict__ A,    // [M,K]
    const float* __restrict__ Bw,   // [N,K]
    const float* __restrict__ bias, // [N]
    float* __restrict__ C,          // [M,N]
    int M, int N, int K, float scale)
{
    __shared__ float As[BK][APAD];
    __shared__ float Bs[BK][APAD];

    const int bm = blockIdx.y * TILE;
    const int bn = blockIdx.x * TILE;
    const int t  = threadIdx.x;
    const int tn = t & 15;   // 0..15 -> column group
    const int tm = t >> 4;   // 0..15 -> row group

    float acc[4][4] = {};

    const int lk = t & 15;   // k within tile for loads
    const int lm = t >> 4;   // 0..15

    for (int k0 = 0; k0 < K; k0 += BK) {
#pragma unroll
        for (int r = 0; r < 4; r++) {
            As[lk][lm + 16 * r] = A[(size_t)(bm + lm + 16 * r) * K + k0 + lk];
            Bs[lk][lm + 16 * r] = Bw[(size_t)(bn + lm + 16 * r) * K + k0 + lk];
        }
        __syncthreads();
#pragma unroll
        for (int kk = 0; kk < BK; kk++) {
            float a[4], b[4];
#pragma unroll
            for (int i = 0; i < 4; i++) a[i] = As[kk][tm * 4 + i];
#pragma unroll
            for (int j = 0; j < 4; j++) b[j] = Bs[kk][tn * 4 + j];
#pragma unroll
            for (int i = 0; i < 4; i++)
#pragma unroll
                for (int j = 0; j < 4; j++)
                    acc[i][j] += a[i] * b[j];
        }
        __syncthreads();
    }

#pragma unroll
    for (int i = 0; i < 4; i++) {
        const int row = bm + tm * 4 + i;
#pragma unroll
        for (int j = 0; j < 4; j++) {
            const int col = bn + tn * 4 + j;
            C[(size_t)row * N + col] = (acc[i][j] + bias[col]) * scale;
        }
    }
}

// ---------------------------------------------------------------------------
// Scores + softmax: one block per (b,h,q) row.
// W[b,h,q,k] = softmax_k( Q[b,q,h*64+:].K[b,k,h*64+:] + bias[b,h,q,k], mask )
// Q is pre-scaled by D^-0.5. mask[b,k] != 0 => -inf.
// ---------------------------------------------------------------------------
__global__ __launch_bounds__(256) void attn_scores(
    const float* __restrict__ Q,     // [B*S, E] (pre-scaled)
    const float* __restrict__ Km,    // [B*S, E]
    const float* __restrict__ bias,  // [B,H,S,S]
    const int*   __restrict__ mask,  // [B,S]
    float* __restrict__ W)           // [B,H,S,S]
{
    const int bid = blockIdx.x;
    const int q = bid & (Sq - 1);
    const int h = (bid >> 10) & (Hq - 1);
    const int b = bid >> 14;

    __shared__ __align__(16) float qs[Dq];
    __shared__ float red[256];

    const int t = threadIdx.x;
    if (t < Dq) qs[t] = Q[((size_t)(b * Sq + q)) * Eq + h * Dq + t];
    __syncthreads();

    const float* Kbase   = Km + (size_t)b * Sq * Eq + h * Dq;
    const float* biasRow = bias + (((size_t)(b * Hq + h) * Sq + q) * Sq);
    const int*   mrow    = mask + b * Sq;

    float sc[4];
    float mx = -INFINITY;
#pragma unroll
    for (int j = 0; j < 4; j++) {
        const int k = t + 256 * j;
        const float4* kr = (const float4*)(Kbase + (size_t)k * Eq);
        const float4* qv = (const float4*)qs;
        float d = 0.f;
#pragma unroll
        for (int c = 0; c < Dq / 4; c++) {
            float4 kv = kr[c];
            float4 qc = qv[c];
            d += kv.x * qc.x + kv.y * qc.y + kv.z * qc.z + kv.w * qc.w;
        }
        d += biasRow[k];
        if (mrow[k] != 0) d = -INFINITY;
        sc[j] = d;
        mx = fmaxf(mx, d);
    }

    // block max
    red[t] = mx;
    __syncthreads();
    for (int s = 128; s > 0; s >>= 1) {
        if (t < s) red[t] = fmaxf(red[t], red[t + s]);
        __syncthreads();
    }
    mx = red[0];
    __syncthreads();

    float lsum = 0.f;
#pragma unroll
    for (int j = 0; j < 4; j++) {
        sc[j] = expf(sc[j] - mx);  // exp(-inf - mx) = 0 for masked
        lsum += sc[j];
    }
    red[t] = lsum;
    __syncthreads();
    for (int s = 128; s > 0; s >>= 1) {
        if (t < s) red[t] += red[t + s];
        __syncthreads();
    }
    const float inv = 1.0f / red[0];

    float* wrow = W + (((size_t)(b * Hq + h) * Sq + q) * Sq);
#pragma unroll
    for (int j = 0; j < 4; j++) {
        wrow[t + 256 * j] = sc[j] * inv;
    }
}

// ---------------------------------------------------------------------------
// PV: AO[b,q,h*64+d] = sum_k W[b,h,q,k] * V[b,k,h*64+d]
// block = 256 threads = 4 q-rows x 64 d. V staged through LDS in 32-row chunks.
// ---------------------------------------------------------------------------
__global__ __launch_bounds__(256) void attn_pv(
    const float* __restrict__ W,  // [B,H,S,S]
    const float* __restrict__ V,  // [B*S, E]
    float* __restrict__ AO)       // [B*S, E]
{
    const int bid = blockIdx.x;
    const int qc = bid & 255;        // group of 4 q rows
    const int h  = (bid >> 8) & (Hq - 1);
    const int b  = bid >> 12;

    const int t  = threadIdx.x;
    const int d  = t & 63;
    const int qi = t >> 6;
    const int q  = qc * 4 + qi;

    __shared__ float Vc[32][64];
    __shared__ float wsm[4][32];

    const float* Vbase = V + (size_t)b * Sq * Eq + h * Dq;
    const float* Wbase = W + ((size_t)(b * Hq + h) * Sq) * Sq;

    float acc = 0.f;
    for (int k0 = 0; k0 < Sq; k0 += 32) {
#pragma unroll
        for (int r = 0; r < 8; r++) {
            const int i = qi * 8 + r;
            Vc[i][d] = Vbase[(size_t)(k0 + i) * Eq + d];
        }
        if (t < 128) {
            const int ii = t & 31, qq = t >> 5;
            wsm[qq][ii] = Wbase[(size_t)(qc * 4 + qq) * Sq + k0 + ii];
        }
        __syncthreads();
#pragma unroll
        for (int i = 0; i < 32; i++) acc += wsm[qi][i] * Vc[i][d];
        __syncthreads();
    }
    AO[(size_t)(b * Sq + q) * Eq + h * Dq + d] = acc;
}

// ---------------------------------------------------------------------------
extern "C" void kernel_launch(void* const* d_in, const int* in_sizes, int n_in,
                              void* d_out, int out_size, void* d_ws, size_t ws_size,
                              hipStream_t stream) {
    const float* x         = (const float*)d_in[0];
    const float* attn_bias = (const float*)d_in[1];
    const int*   mask      = (const int*)d_in[2];
    const float* Wq = (const float*)d_in[3];
    const float* bq = (const float*)d_in[4];
    const float* Wk = (const float*)d_in[5];
    const float* bk = (const float*)d_in[6];
    const float* Wv = (const float*)d_in[7];
    const float* bv = (const float*)d_in[8];
    const float* Wo = (const float*)d_in[9];
    const float* bo = (const float*)d_in[10];

    float* out    = (float*)d_out;                       // [B,S,E]
    float* attn_w = out + (size_t)Bq * Sq * Eq;          // [B,H,S,S]

    const size_t rows = (size_t)Bq * Sq;                 // 4096
    float* Q  = (float*)d_ws;                            // [4096,1024]
    float* K  = Q + rows * Eq;
    float* V  = K + rows * Eq;
    float* AO = Q;  // reuse Q's slot after scores are done

    const dim3 gemm_grid(Eq / TILE, (int)(rows / TILE)); // 16 x 64
    const float scaling = 0.125f;                        // D^-0.5

    gemm_bt<<<gemm_grid, 256, 0, stream>>>(x, Wq, bq, Q, (int)rows, Eq, Eq, scaling);
    gemm_bt<<<gemm_grid, 256, 0, stream>>>(x, Wk, bk, K, (int)rows, Eq, Eq, 1.0f);
    gemm_bt<<<gemm_grid, 256, 0, stream>>>(x, Wv, bv, V, (int)rows, Eq, Eq, 1.0f);

    attn_scores<<<Bq * Hq * Sq, 256, 0, stream>>>(Q, K, attn_bias, mask, attn_w);
    attn_pv<<<Bq * Hq * (Sq / 4), 256, 0, stream>>>(attn_w, V, AO);

    gemm_bt<<<gemm_grid, 256, 0, stream>>>(AO, Wo, bo, out, (int)rows, Eq, Eq, 1.0f);
}